// Round 4
// baseline (142.492 us; speedup 1.0000x reference)
//
#include <hip/hip_runtime.h>

// Packed volume-render (NeRF ray compositing).
// Pass 1: stream ridx (int4), write per-ray segment start offsets into d_ws.
// Pass 2: EIGHT THREADS PER RAY (chunked associative scan-combine):
//   - ray segment split into 8 contiguous chunks, one thread each
//     (R*8 = 524288 threads -> 8192 waves -> 100% occupancy cap, vs 12.5%
//      for thread-per-ray which measured VALUBusy 2.7% / occ 9.9%)
//   - each thread: local transmittance scan (T=1 start, one __expf/sample),
//     local accumulators (w, w*rgb, w*depth) + local sum of tau
//   - 8-lane segmented combine in-register: guarded shfl_up prefix of tau,
//     scale accumulators by exp(-excl_prefix), shfl_xor butterfly sum
//   - chunk-local early exit at T<1e-5 is sound: truncated chunk still has
//     sum(tau) >= 11.5 so downstream weights <= 1e-5, and per-chunk sum(w)<=1.

#define K_CHUNKS 8

__global__ __launch_bounds__(256) void starts_kernel(
    const int* __restrict__ ridx, int* __restrict__ starts,
    int n_samples, int n_rays)
{
    const int t = blockIdx.x * blockDim.x + threadIdx.x;
    const int i0 = t * 4;
    if (i0 >= n_samples) return;

    int prev = (i0 == 0) ? -1 : ridx[i0 - 1];
    const int nj = min(4, n_samples - i0);
    if (nj == 4) {
        const int4 v = *reinterpret_cast<const int4*>(ridx + i0);
        const int cur[4] = {v.x, v.y, v.z, v.w};
        #pragma unroll
        for (int j = 0; j < 4; ++j) {
            const int c = cur[j];
            for (int r = prev + 1; r <= c; ++r) starts[r] = i0 + j;
            prev = c;
        }
    } else {
        for (int j = 0; j < nj; ++j) {
            const int c = ridx[i0 + j];
            for (int r = prev + 1; r <= c; ++r) starts[r] = i0 + j;
            prev = c;
        }
    }
    if (i0 + 4 >= n_samples) {       // last thread closes the table
        for (int r = prev + 1; r <= n_rays; ++r) starts[r] = n_samples;
    }
}

__device__ __forceinline__ void sample1(
    float dens, float del, float c0, float c1, float c2, float dp,
    float& T, float& tsum, float& aw, float& ar, float& ag, float& ab, float& ad)
{
    const float tau = dens * del;
    const float e = __expf(-tau);
    const float w = T * (1.0f - e);
    T *= e;
    tsum += tau;
    aw += w;
    ar += w * c0;
    ag += w * c1;
    ab += w * c2;
    ad += w * dp;
}

template <bool USE_STARTS>
__global__ __launch_bounds__(256) void render_kernel(
    const float* __restrict__ color,    // [N,3]
    const float* __restrict__ density,  // [N,1]
    const float* __restrict__ deltas,   // [N,1]
    const float* __restrict__ depths,   // [N,1]
    const int*   __restrict__ ridx,     // [N] sorted (fallback path only)
    const int*   __restrict__ starts,   // [R+1]
    float*       __restrict__ out,      // rgb[3R] | depth[R] | alpha[R] | hit[R]
    int n_samples, int n_rays)
{
    const int tid = blockIdx.x * blockDim.x + threadIdx.x;
    const int r = tid >> 3;             // ray id
    const int j = tid & (K_CHUNKS - 1); // chunk id within ray
    if (r >= n_rays) return;

    int start, end;
    if (USE_STARTS) {
        start = starts[r];
        end   = starts[r + 1];
    } else {
        int lo = 0, hi = n_samples;                 // lower_bound(r)
        while (lo < hi) { int m = (lo + hi) >> 1; if (ridx[m] < r) lo = m + 1; else hi = m; }
        start = lo;
        int lo2 = lo; hi = n_samples;               // lower_bound(r+1)
        while (lo2 < hi) { int m = (lo2 + hi) >> 1; if (ridx[m] < r + 1) lo2 = m + 1; else hi = m; }
        end = lo2;
    }

    const int len   = end - start;
    const int chunk = (len + K_CHUNKS - 1) >> 3;
    int i   = min(start + j * chunk, end);
    const int e1 = min(i + chunk, end);

    float T = 1.0f, tsum = 0.0f;
    float aw = 0.0f, ar = 0.0f, ag = 0.0f, ab = 0.0f, ad = 0.0f;
    const float TEPS = 1e-5f;

    // scalar peel to 4-sample alignment
    while (i < e1 && (i & 3) && T > TEPS) {
        sample1(density[i], deltas[i],
                color[3 * i], color[3 * i + 1], color[3 * i + 2], depths[i],
                T, tsum, aw, ar, ag, ab, ad);
        ++i;
    }
    // vectorized main loop: 4 samples/iter, all loads 16B aligned
    for (; i + 4 <= e1 && T > TEPS; i += 4) {
        const float4 dn = *reinterpret_cast<const float4*>(density + i);
        const float4 dl = *reinterpret_cast<const float4*>(deltas + i);
        const float4 dp = *reinterpret_cast<const float4*>(depths + i);
        const float4* c4 = reinterpret_cast<const float4*>(color + 3 * i);
        const float4 ca = c4[0], cb = c4[1], cc = c4[2];
        sample1(dn.x, dl.x, ca.x, ca.y, ca.z, dp.x, T, tsum, aw, ar, ag, ab, ad);
        sample1(dn.y, dl.y, ca.w, cb.x, cb.y, dp.y, T, tsum, aw, ar, ag, ab, ad);
        sample1(dn.z, dl.z, cb.z, cb.w, cc.x, dp.z, T, tsum, aw, ar, ag, ab, ad);
        sample1(dn.w, dl.w, cc.y, cc.z, cc.w, dp.w, T, tsum, aw, ar, ag, ab, ad);
    }
    // scalar tail
    while (i < e1 && T > TEPS) {
        sample1(density[i], deltas[i],
                color[3 * i], color[3 * i + 1], color[3 * i + 2], depths[i],
                T, tsum, aw, ar, ag, ab, ad);
        ++i;
    }

    // ---- 8-lane segmented combine (lanes j=0..7 of this ray) ----
    // inclusive prefix of tsum within the 8-lane group (guard keeps it segmented)
    float p = tsum;
    #pragma unroll
    for (int o = 1; o < K_CHUNKS; o <<= 1) {
        const float y = __shfl_up(p, o);
        if (j >= o) p += y;
    }
    const float s = __expf(-(p - tsum));   // exp(-exclusive prefix)
    aw *= s; ar *= s; ag *= s; ab *= s; ad *= s;

    // butterfly sum across the 8-lane group (xor of 1,2,4 stays in-group)
    #pragma unroll
    for (int o = 1; o < K_CHUNKS; o <<= 1) {
        aw += __shfl_xor(aw, o);
        ar += __shfl_xor(ar, o);
        ag += __shfl_xor(ag, o);
        ab += __shfl_xor(ab, o);
        ad += __shfl_xor(ad, o);
    }

    if (j == 0) {
        const float alpha = aw;
        out[3 * r + 0] = (1.0f - alpha) + alpha * ar;   // white background composite
        out[3 * r + 1] = (1.0f - alpha) + alpha * ag;
        out[3 * r + 2] = (1.0f - alpha) + alpha * ab;
        out[3 * n_rays + r] = ad;                       // depth
        out[4 * n_rays + r] = alpha;                    // alpha
        out[5 * n_rays + r] = (alpha > 0.0f) ? 1.0f : 0.0f;  // hit
    }
}

extern "C" void kernel_launch(void* const* d_in, const int* in_sizes, int n_in,
                              void* d_out, int out_size, void* d_ws, size_t ws_size,
                              hipStream_t stream) {
    const float* color   = (const float*)d_in[0];
    const float* density = (const float*)d_in[1];
    const float* deltas  = (const float*)d_in[2];
    const float* depths  = (const float*)d_in[3];
    const int*   ridx    = (const int*)d_in[4];
    float* out = (float*)d_out;

    const int n_samples = in_sizes[1];      // density element count == N
    const int n_rays    = out_size / 6;     // rgb(3R) + depth(R) + alpha(R) + hit(R)

    const size_t starts_bytes = (size_t)(n_rays + 1) * sizeof(int);
    const long long nthr = (long long)n_rays * K_CHUNKS;
    const int rblocks = (int)((nthr + 255) / 256);

    if (ws_size >= starts_bytes) {
        int* starts = (int*)d_ws;
        const int snthreads = (n_samples + 3) / 4;
        const int sblocks = (snthreads + 255) / 256;
        starts_kernel<<<sblocks, 256, 0, stream>>>(ridx, starts, n_samples, n_rays);
        render_kernel<true><<<rblocks, 256, 0, stream>>>(
            color, density, deltas, depths, ridx, starts, out, n_samples, n_rays);
    } else {
        render_kernel<false><<<rblocks, 256, 0, stream>>>(
            color, density, deltas, depths, ridx, (const int*)nullptr, out,
            n_samples, n_rays);
    }
}

// Round 6
// 72.442 us; speedup vs baseline: 1.9670x; 1.9670x over previous
//
#include <hip/hip_runtime.h>

// Packed volume-render (NeRF ray compositing) — sample-parallel segmented scan.
//
// Pass 0 (zero_kernel):  zero the per-ray piece table in d_ws.
// Pass 1 (scan_kernel):  blocks of 2048 contiguous samples, 256 thr x 8 samples.
//   - coalesced int4/float4 loads of ridx/density/deltas (+color/depths unless
//     the thread's whole range is extinct: piece-local prefix >= 12 -> skip)
//   - 256-thread segmented scan of tau (wave shfl + 4-wave LDS combine) gives
//     each thread its piece-local tau prefix
//   - thread-serial walk emits micro-pieces (Σtau, Σw, Σw·rgb, Σw·d scaled by
//     exp(-prefix)) into per-ray LDS slots via atomicAdd; also writes the
//     starts[] table at ray boundaries (fused -- no separate ridx pass)
//   - ROUND-5 BUG FIX: the starts[] table closing (entries past the last ray)
//     was inside the non-skip walk branch; the last thread is usually in an
//     extinct tail (skipC) so starts[n_rays] stayed garbage -> combine read
//     e<s for the last ray -> rgb=1. Closing is now hoisted so the last valid
//     thread always runs it.
//   - block flushes LDS slots to pieces[(ray<<1)|(block&1)] with plain stores
//     (a ray spans <=2 consecutive blocks since max ray len << 2048, so each
//     piece slot has a unique writer; longer rays -> combine-side fallback)
// Pass 2 (combine_kernel): thread per ray: T=1; acc += T*piece; T *= exp(-Σtau);
//   white-background composite and output.

#define SPB        2048
#define SPB_SHIFT  11
#define TPB        256
#define SPT        8
#define NSLOT      192
#define THR_SKIP   12.0f

__global__ __launch_bounds__(256) void zero_kernel(float4* __restrict__ p, int n4) {
    const int i = blockIdx.x * blockDim.x + threadIdx.x;
    if (i < n4) p[i] = make_float4(0.f, 0.f, 0.f, 0.f);
}

__device__ __forceinline__ void flush_piece(
    float (*s_acc)[6], float* __restrict__ pieces, int b, int rfirst, int r,
    float pfx, float ts, float aw, float ar, float ag, float ab, float ad)
{
    const float sc = __expf(-pfx);
    const int slot = r - rfirst;
    if (slot >= 0 && slot < NSLOT) {
        atomicAdd(&s_acc[slot][0], ts);
        atomicAdd(&s_acc[slot][1], sc * aw);
        atomicAdd(&s_acc[slot][2], sc * ar);
        atomicAdd(&s_acc[slot][3], sc * ag);
        atomicAdd(&s_acc[slot][4], sc * ab);
        atomicAdd(&s_acc[slot][5], sc * ad);
    } else {                       // never taken for this input; general fallback
        float* P = pieces + 6 * (((size_t)r << 1) | (size_t)(b & 1));
        atomicAdd(P + 0, ts);
        atomicAdd(P + 1, sc * aw);
        atomicAdd(P + 2, sc * ar);
        atomicAdd(P + 3, sc * ag);
        atomicAdd(P + 4, sc * ab);
        atomicAdd(P + 5, sc * ad);
    }
}

__global__ __launch_bounds__(256) void scan_kernel(
    const float* __restrict__ color,    // [N,3]
    const float* __restrict__ density,  // [N,1]
    const float* __restrict__ deltas,   // [N,1]
    const float* __restrict__ depths,   // [N,1]
    const int*   __restrict__ ridx,     // [N] sorted
    int*         __restrict__ starts,   // [R+1] (written here)
    float*       __restrict__ pieces,   // [R*2][6]
    int n_samples, int n_rays)
{
    __shared__ float s_acc[NSLOT][6];
    __shared__ float s_wv[TPB / 64];
    __shared__ int   s_wf[TPB / 64];

    const int tid  = threadIdx.x;
    const int lane = tid & 63;
    const int wid  = tid >> 6;
    const int b    = blockIdx.x;
    const int i0   = b * SPB + tid * SPT;

    for (int k = tid; k < NSLOT * 6; k += TPB) (&s_acc[0][0])[k] = 0.0f;
    __syncthreads();

    const int rfirst = ridx[min(b * SPB, n_samples - 1)];

    // ---- phase 1: ridx + tau (always loaded; scan input) ----
    int   rr[SPT];
    float tau[SPT];
    const int nvalid = max(0, min(SPT, n_samples - i0));

    if (nvalid == SPT) {
        const int4 ia = *reinterpret_cast<const int4*>(ridx + i0);
        const int4 ib = *reinterpret_cast<const int4*>(ridx + i0 + 4);
        rr[0]=ia.x; rr[1]=ia.y; rr[2]=ia.z; rr[3]=ia.w;
        rr[4]=ib.x; rr[5]=ib.y; rr[6]=ib.z; rr[7]=ib.w;
        const float4 na = *reinterpret_cast<const float4*>(density + i0);
        const float4 nb = *reinterpret_cast<const float4*>(density + i0 + 4);
        const float4 la = *reinterpret_cast<const float4*>(deltas  + i0);
        const float4 lb = *reinterpret_cast<const float4*>(deltas  + i0 + 4);
        tau[0]=na.x*la.x; tau[1]=na.y*la.y; tau[2]=na.z*la.z; tau[3]=na.w*la.w;
        tau[4]=nb.x*lb.x; tau[5]=nb.y*lb.y; tau[6]=nb.z*lb.z; tau[7]=nb.w*lb.w;
    } else {
        const int rpad = (n_samples > 0) ? ridx[n_samples - 1] : 0;
        for (int j = 0; j < SPT; ++j) {
            const int idx = i0 + j;
            if (idx < n_samples) { rr[j] = ridx[idx]; tau[j] = density[idx] * deltas[idx]; }
            else                 { rr[j] = rpad;      tau[j] = 0.0f; }
        }
    }
    const int prev_r = (i0 == 0) ? -1 : ridx[min(i0, n_samples) - 1];

    // trailing tau-sum (samples belonging to the last ray in range) + boundary flag
    const int rtail = rr[SPT - 1];
    float val = 0.f;
    #pragma unroll
    for (int j = 0; j < SPT; ++j) if (rr[j] == rtail) val += tau[j];
    int flg = (prev_r != rtail) ? 1 : 0;

    // ---- segmented inclusive scan across the block's 256 threads ----
    float v = val; int f = flg;
    #pragma unroll
    for (int o = 1; o < 64; o <<= 1) {
        const float vy = __shfl_up(v, o);
        const int   fy = __shfl_up(f, o);
        if (lane >= o) { v = f ? v : (vy + v); f |= fy; }
    }
    float ev = __shfl_up(v, 1);
    int   ef = __shfl_up(f, 1);
    if (lane == 0) { ev = 0.f; ef = 0; }
    if (lane == 63) { s_wv[wid] = v; s_wf[wid] = f; }
    __syncthreads();
    float ov = 0.f;
    for (int w = 0; w < wid; ++w) {
        const float bv = s_wv[w]; const int bf = s_wf[w];
        ov = bf ? bv : (ov + bv);
    }
    const float pv = ef ? ev : (ov + ev);   // tau-sum from piece start to thread start

    // ---- table closing: ALWAYS runs on the last valid thread (bug fix) ----
    if (nvalid > 0 && i0 + SPT >= n_samples) {
        for (int q = rtail + 1; q <= n_rays; ++q) starts[q] = n_samples;
    }

    // ---- phase 2: colors/depths + thread-serial walk ----
    const bool noBnd = (prev_r == rtail);
    const bool skipC = noBnd && (pv >= THR_SKIP) && (nvalid > 0);

    if (nvalid > 0) {
        if (skipC) {
            // whole thread extinct: weights <= e^-12, only Σtau matters
            flush_piece(s_acc, pieces, b, rfirst, rtail, 0.f, val, 0.f, 0.f, 0.f, 0.f, 0.f);
        } else {
            float c0[SPT], c1[SPT], c2[SPT], dpv[SPT];
            if (nvalid == SPT) {
                const float4* cp = reinterpret_cast<const float4*>(color + 3 * i0);
                const float4 A=cp[0],B=cp[1],C=cp[2],D=cp[3],E=cp[4],F=cp[5];
                c0[0]=A.x; c1[0]=A.y; c2[0]=A.z;
                c0[1]=A.w; c1[1]=B.x; c2[1]=B.y;
                c0[2]=B.z; c1[2]=B.w; c2[2]=C.x;
                c0[3]=C.y; c1[3]=C.z; c2[3]=C.w;
                c0[4]=D.x; c1[4]=D.y; c2[4]=D.z;
                c0[5]=D.w; c1[5]=E.x; c2[5]=E.y;
                c0[6]=E.z; c1[6]=E.w; c2[6]=F.x;
                c0[7]=F.y; c1[7]=F.z; c2[7]=F.w;
                const float4 pa = *reinterpret_cast<const float4*>(depths + i0);
                const float4 pb = *reinterpret_cast<const float4*>(depths + i0 + 4);
                dpv[0]=pa.x; dpv[1]=pa.y; dpv[2]=pa.z; dpv[3]=pa.w;
                dpv[4]=pb.x; dpv[5]=pb.y; dpv[6]=pb.z; dpv[7]=pb.w;
            } else {
                for (int j = 0; j < SPT; ++j) {
                    const int idx = i0 + j;
                    if (idx < n_samples) {
                        c0[j]=color[3*idx]; c1[j]=color[3*idx+1]; c2[j]=color[3*idx+2];
                        dpv[j]=depths[idx];
                    } else { c0[j]=c1[j]=c2[j]=dpv[j]=0.f; }
                }
            }

            int   cur = prev_r;
            float pfx = pv;
            float T = 1.f, ts = 0.f, aw=0.f, ar=0.f, ag=0.f, ab=0.f, ad=0.f;
            bool  open = false;
            #pragma unroll
            for (int j = 0; j < SPT; ++j) {
                if (i0 + j >= n_samples) break;
                const int rj = rr[j];
                if (rj != cur) {
                    if (open) flush_piece(s_acc, pieces, b, rfirst, cur, pfx, ts, aw, ar, ag, ab, ad);
                    for (int q = cur + 1; q <= rj; ++q) starts[q] = i0 + j;
                    cur = rj; pfx = 0.f; T = 1.f;
                    ts = aw = ar = ag = ab = ad = 0.f; open = false;
                }
                const float e = __expf(-tau[j]);
                const float w = T * (1.f - e);
                T *= e; ts += tau[j];
                aw += w; ar += w * c0[j]; ag += w * c1[j]; ab += w * c2[j]; ad += w * dpv[j];
                open = true;
            }
            if (open) flush_piece(s_acc, pieces, b, rfirst, cur, pfx, ts, aw, ar, ag, ab, ad);
        }
    }
    __syncthreads();

    // ---- flush LDS slots to the piece table (unique writer per slot) ----
    const int rlastB = ridx[min(b * SPB + SPB, n_samples) - 1];
    const int nuse = min(rlastB - rfirst + 1, NSLOT);
    for (int s = tid; s < nuse; s += TPB) {
        float* P = pieces + 6 * (((size_t)(rfirst + s) << 1) | (size_t)(b & 1));
        P[0]=s_acc[s][0]; P[1]=s_acc[s][1]; P[2]=s_acc[s][2];
        P[3]=s_acc[s][3]; P[4]=s_acc[s][4]; P[5]=s_acc[s][5];
    }
}

__global__ __launch_bounds__(256) void combine_kernel(
    const float* __restrict__ color, const float* __restrict__ density,
    const float* __restrict__ deltas, const float* __restrict__ depths,
    const int* __restrict__ starts, const float* __restrict__ pieces,
    float* __restrict__ out, int n_rays)
{
    const int r = blockIdx.x * blockDim.x + threadIdx.x;
    if (r >= n_rays) return;
    const int s = starts[r], e = starts[r + 1];
    float T = 1.f, aw = 0.f, ar = 0.f, ag = 0.f, ab = 0.f, ad = 0.f;
    if (e - s <= SPB) {
        if (s < e) {
            const int b0 = s >> SPB_SHIFT, bE = (e - 1) >> SPB_SHIFT;
            for (int b = b0; b <= bE; ++b) {
                const float* P = pieces + 6 * (((size_t)r << 1) | (size_t)(b & 1));
                aw += T * P[1]; ar += T * P[2]; ag += T * P[3];
                ab += T * P[4]; ad += T * P[5];
                T *= __expf(-P[0]);
            }
        }
    } else {                      // general fallback: serial walk (never for this input)
        for (int i = s; i < e; ++i) {
            const float t = density[i] * deltas[i];
            const float ee = __expf(-t);
            const float w = T * (1.f - ee);
            aw += w; ar += w * color[3*i]; ag += w * color[3*i+1];
            ab += w * color[3*i+2]; ad += w * depths[i];
            T *= ee;
        }
    }
    const float alpha = aw;
    out[3 * r + 0] = (1.0f - alpha) + alpha * ar;
    out[3 * r + 1] = (1.0f - alpha) + alpha * ag;
    out[3 * r + 2] = (1.0f - alpha) + alpha * ab;
    out[3 * n_rays + r] = ad;
    out[4 * n_rays + r] = alpha;
    out[5 * n_rays + r] = (alpha > 0.0f) ? 1.0f : 0.0f;
}

// ---------------- fallback path (round-3, known good) ----------------
__global__ __launch_bounds__(256) void starts_kernel(
    const int* __restrict__ ridx, int* __restrict__ starts,
    int n_samples, int n_rays)
{
    const int t = blockIdx.x * blockDim.x + threadIdx.x;
    const int i0 = t * 4;
    if (i0 >= n_samples) return;
    int prev = (i0 == 0) ? -1 : ridx[i0 - 1];
    const int nj = min(4, n_samples - i0);
    for (int j = 0; j < nj; ++j) {
        const int c = ridx[i0 + j];
        for (int r = prev + 1; r <= c; ++r) starts[r] = i0 + j;
        prev = c;
    }
    if (i0 + 4 >= n_samples)
        for (int r = prev + 1; r <= n_rays; ++r) starts[r] = n_samples;
}

__global__ __launch_bounds__(256) void render_fallback(
    const float* __restrict__ color, const float* __restrict__ density,
    const float* __restrict__ deltas, const float* __restrict__ depths,
    const int* __restrict__ starts, float* __restrict__ out, int n_rays)
{
    const int r = blockIdx.x * blockDim.x + threadIdx.x;
    if (r >= n_rays) return;
    int i = starts[r]; const int e = starts[r + 1];
    float T = 1.f, aw = 0.f, ar = 0.f, ag = 0.f, ab = 0.f, ad = 0.f;
    for (; i < e && T > 1e-5f; ++i) {
        const float t = density[i] * deltas[i];
        const float ee = __expf(-t);
        const float w = T * (1.f - ee);
        aw += w; ar += w * color[3*i]; ag += w * color[3*i+1];
        ab += w * color[3*i+2]; ad += w * depths[i];
        T *= ee;
    }
    const float alpha = aw;
    out[3 * r + 0] = (1.0f - alpha) + alpha * ar;
    out[3 * r + 1] = (1.0f - alpha) + alpha * ag;
    out[3 * r + 2] = (1.0f - alpha) + alpha * ab;
    out[3 * n_rays + r] = ad;
    out[4 * n_rays + r] = alpha;
    out[5 * n_rays + r] = (alpha > 0.0f) ? 1.0f : 0.0f;
}

extern "C" void kernel_launch(void* const* d_in, const int* in_sizes, int n_in,
                              void* d_out, int out_size, void* d_ws, size_t ws_size,
                              hipStream_t stream) {
    const float* color   = (const float*)d_in[0];
    const float* density = (const float*)d_in[1];
    const float* deltas  = (const float*)d_in[2];
    const float* depths  = (const float*)d_in[3];
    const int*   ridx    = (const int*)d_in[4];
    float* out = (float*)d_out;

    const int n_samples = in_sizes[1];
    const int n_rays    = out_size / 6;

    const size_t startsB = (((size_t)(n_rays + 1) * sizeof(int)) + 15) & ~(size_t)15;
    const size_t piecesB = (size_t)n_rays * 12 * sizeof(float);

    if (ws_size >= startsB + piecesB) {
        int*   starts = (int*)d_ws;
        float* pieces = (float*)((char*)d_ws + startsB);
        const int n4 = n_rays * 3;                       // float4 count of pieces
        zero_kernel<<<(n4 + 255) / 256, 256, 0, stream>>>((float4*)pieces, n4);
        const int nb = (n_samples + SPB - 1) / SPB;
        scan_kernel<<<nb, TPB, 0, stream>>>(color, density, deltas, depths, ridx,
                                            starts, pieces, n_samples, n_rays);
        combine_kernel<<<(n_rays + 255) / 256, 256, 0, stream>>>(
            color, density, deltas, depths, starts, pieces, out, n_rays);
    } else {
        int* starts = (int*)d_ws;                        // round-3 fallback
        const int snthreads = (n_samples + 3) / 4;
        starts_kernel<<<(snthreads + 255) / 256, 256, 0, stream>>>(ridx, starts,
                                                                   n_samples, n_rays);
        render_fallback<<<(n_rays + 255) / 256, 256, 0, stream>>>(
            color, density, deltas, depths, starts, out, n_rays);
    }
}

// Round 7
// 32.778 us; speedup vs baseline: 4.3472x; 2.2101x over previous
//
#include <hip/hip_runtime.h>

// Packed volume-render (NeRF ray compositing).
// Pass 1 (starts_kernel): stream ridx (int4), write per-ray segment starts.
// Pass 2 (render_kernel): SIXTEEN LANES PER RAY:
//   - R*16 = 1M threads = 16384 waves (occupancy-rich; R3's thread-per-ray
//     had only 1024 waves / 9.9% occ, R2's wave-per-ray burned 6-step scans)
//   - each group reads 16 CONSECUTIVE samples per chunk -> every 64B line is
//     fully consumed by the instruction that fetches it (no R4-style reuse
//     window -> no L2 thrash)
//   - 4-step width-16 shfl_up segmented scan of tau per chunk + running carry
//   - extinction break when carry >= 12 (group-uniform, checked at chunk end
//     so it never gates the current chunk's loads): remaining weights
//     <= e^-12, error ~6e-6 << 2e-2 threshold; cuts ~128 -> ~52 samples/ray
//   - 4-step group reduction, lane 0 of the group writes all outputs.

#define THR_TAU 12.0f

__global__ __launch_bounds__(256) void starts_kernel(
    const int* __restrict__ ridx, int* __restrict__ starts,
    int n_samples, int n_rays)
{
    const int t = blockIdx.x * blockDim.x + threadIdx.x;
    const int i0 = t * 4;
    if (i0 >= n_samples) return;

    int prev = (i0 == 0) ? -1 : ridx[i0 - 1];
    const int nj = min(4, n_samples - i0);
    if (nj == 4) {
        const int4 v = *reinterpret_cast<const int4*>(ridx + i0);
        const int cur[4] = {v.x, v.y, v.z, v.w};
        #pragma unroll
        for (int j = 0; j < 4; ++j) {
            const int c = cur[j];
            for (int r = prev + 1; r <= c; ++r) starts[r] = i0 + j;
            prev = c;
        }
    } else {
        for (int j = 0; j < nj; ++j) {
            const int c = ridx[i0 + j];
            for (int r = prev + 1; r <= c; ++r) starts[r] = i0 + j;
            prev = c;
        }
    }
    if (i0 + 4 >= n_samples) {       // last thread closes the table
        for (int r = prev + 1; r <= n_rays; ++r) starts[r] = n_samples;
    }
}

__global__ __launch_bounds__(256) void render_kernel(
    const float* __restrict__ color,    // [N,3]
    const float* __restrict__ density,  // [N,1]
    const float* __restrict__ deltas,   // [N,1]
    const float* __restrict__ depths,   // [N,1]
    const int*   __restrict__ starts,   // [R+1]
    float*       __restrict__ out,      // rgb[3R] | depth[R] | alpha[R] | hit[R]
    int n_rays)
{
    const int tid = blockIdx.x * blockDim.x + threadIdx.x;
    const int r   = tid >> 4;           // ray id (16 lanes per ray)
    const int sub = tid & 15;           // lane within group
    if (r >= n_rays) return;

    const int start = starts[r];
    const int end   = starts[r + 1];

    float carry = 0.0f;                 // cumulative tau from previous chunks
    float aw = 0.0f, ar = 0.0f, ag = 0.0f, ab = 0.0f, ad = 0.0f;

    for (int base = start; base < end; base += 16) {
        const int i = base + sub;
        const bool valid = (i < end);
        float tau = 0.0f, c0 = 0.0f, c1 = 0.0f, c2 = 0.0f, dp = 0.0f;
        if (valid) {
            tau = density[i] * deltas[i];
            c0  = color[3 * i + 0];
            c1  = color[3 * i + 1];
            c2  = color[3 * i + 2];
            dp  = depths[i];
        }
        // inclusive scan of tau within the 16-lane group
        float x = tau;
        #pragma unroll
        for (int o = 1; o < 16; o <<= 1) {
            const float y = __shfl_up(x, o, 16);
            if (sub >= o) x += y;
        }
        const float excl = carry + (x - tau);       // exclusive segmented cumsum
        const float w = __expf(-excl) * (1.0f - __expf(-tau));
        aw += w;
        ar += w * c0;
        ag += w * c1;
        ab += w * c2;
        ad += w * dp;
        carry += __shfl(x, 15, 16);                 // chunk total (invalid lanes add 0)
        if (carry >= THR_TAU) break;                // extinction: rest weighs <= e^-12
    }

    // reduction across the 16-lane group
    #pragma unroll
    for (int o = 8; o > 0; o >>= 1) {
        aw += __shfl_xor(aw, o, 16);
        ar += __shfl_xor(ar, o, 16);
        ag += __shfl_xor(ag, o, 16);
        ab += __shfl_xor(ab, o, 16);
        ad += __shfl_xor(ad, o, 16);
    }

    if (sub == 0) {
        const float alpha = aw;
        out[3 * r + 0] = (1.0f - alpha) + alpha * ar;   // white background composite
        out[3 * r + 1] = (1.0f - alpha) + alpha * ag;
        out[3 * r + 2] = (1.0f - alpha) + alpha * ab;
        out[3 * n_rays + r] = ad;                       // depth
        out[4 * n_rays + r] = alpha;                    // alpha
        out[5 * n_rays + r] = (alpha > 0.0f) ? 1.0f : 0.0f;  // hit
    }
}

// ---------------- fallback (ws too small): thread-per-ray, binary search ----
__global__ __launch_bounds__(256) void render_fallback(
    const float* __restrict__ color, const float* __restrict__ density,
    const float* __restrict__ deltas, const float* __restrict__ depths,
    const int* __restrict__ ridx, float* __restrict__ out,
    int n_samples, int n_rays)
{
    const int r = blockIdx.x * blockDim.x + threadIdx.x;
    if (r >= n_rays) return;
    int lo = 0, hi = n_samples;
    while (lo < hi) { int m = (lo + hi) >> 1; if (ridx[m] < r) lo = m + 1; else hi = m; }
    int i = lo; int lo2 = lo; hi = n_samples;
    while (lo2 < hi) { int m = (lo2 + hi) >> 1; if (ridx[m] < r + 1) lo2 = m + 1; else hi = m; }
    const int e = lo2;
    float T = 1.f, aw = 0.f, ar = 0.f, ag = 0.f, ab = 0.f, ad = 0.f;
    for (; i < e && T > 1e-5f; ++i) {
        const float t = density[i] * deltas[i];
        const float ee = __expf(-t);
        const float w = T * (1.f - ee);
        aw += w; ar += w * color[3*i]; ag += w * color[3*i+1];
        ab += w * color[3*i+2]; ad += w * depths[i];
        T *= ee;
    }
    const float alpha = aw;
    out[3 * r + 0] = (1.0f - alpha) + alpha * ar;
    out[3 * r + 1] = (1.0f - alpha) + alpha * ag;
    out[3 * r + 2] = (1.0f - alpha) + alpha * ab;
    out[3 * n_rays + r] = ad;
    out[4 * n_rays + r] = alpha;
    out[5 * n_rays + r] = (alpha > 0.0f) ? 1.0f : 0.0f;
}

extern "C" void kernel_launch(void* const* d_in, const int* in_sizes, int n_in,
                              void* d_out, int out_size, void* d_ws, size_t ws_size,
                              hipStream_t stream) {
    const float* color   = (const float*)d_in[0];
    const float* density = (const float*)d_in[1];
    const float* deltas  = (const float*)d_in[2];
    const float* depths  = (const float*)d_in[3];
    const int*   ridx    = (const int*)d_in[4];
    float* out = (float*)d_out;

    const int n_samples = in_sizes[1];      // density element count == N
    const int n_rays    = out_size / 6;     // rgb(3R) + depth(R) + alpha(R) + hit(R)

    const size_t starts_bytes = (size_t)(n_rays + 1) * sizeof(int);

    if (ws_size >= starts_bytes) {
        int* starts = (int*)d_ws;
        const int snthreads = (n_samples + 3) / 4;
        const int sblocks = (snthreads + 255) / 256;
        starts_kernel<<<sblocks, 256, 0, stream>>>(ridx, starts, n_samples, n_rays);

        const long long nthr = (long long)n_rays * 16;
        const int rblocks = (int)((nthr + 255) / 256);
        render_kernel<<<rblocks, 256, 0, stream>>>(
            color, density, deltas, depths, starts, out, n_rays);
    } else {
        const int rblocks = (n_rays + 255) / 256;
        render_fallback<<<rblocks, 256, 0, stream>>>(
            color, density, deltas, depths, ridx, out, n_samples, n_rays);
    }
}

// Round 8
// 27.637 us; speedup vs baseline: 5.1559x; 1.1860x over previous
//
#include <hip/hip_runtime.h>

// Packed volume-render (NeRF ray compositing).
// Pass 1 (starts_kernel): stream ridx (int4), write per-ray segment starts.
// Pass 2 (render_kernel): SIXTEEN LANES PER RAY:
//   - R*16 = 1M threads = 16384 waves
//   - each group reads 16 CONSECUTIVE samples per chunk (full line use)
//   - segmented scan of tau via DPP row_shr (16-lane rows == our groups;
//     bound_ctrl 0-fill segments at the group boundary for free) -- replaces
//     4 serial ds_bpermute per chunk + 20 in the epilogue with ~2-cyc VALU ops
//   - extinction break when carry >= 7 (group-uniform, checked at chunk end):
//     dropped tail <= e^-7 ~ 9e-4 on alpha, ~2e-3 on rgb << 2e-2 threshold
//   - Hillis-Steele leaves group totals in lane 15 -> lane 15 writes outputs.

#define THR_TAU 7.0f

__device__ __forceinline__ float dpp_shr_add(float x, const int ctrl_unused) {
    return x;  // placeholder (specializations below via template)
}

template <int CTRL>
__device__ __forceinline__ float dpp_mov0(float v) {
    // value of lane (i - shr) within the 16-lane DPP row; 0 if out of row
    const int r = __builtin_amdgcn_update_dpp(
        0, __float_as_int(v), CTRL, 0xf, 0xf, true);
    return __int_as_float(r);
}

__device__ __forceinline__ float row16_inclusive_scan(float x) {
    x += dpp_mov0<0x111>(x);   // row_shr:1
    x += dpp_mov0<0x112>(x);   // row_shr:2
    x += dpp_mov0<0x114>(x);   // row_shr:4
    x += dpp_mov0<0x118>(x);   // row_shr:8
    return x;                  // lane 15 of each row holds the row total
}

__global__ __launch_bounds__(256) void starts_kernel(
    const int* __restrict__ ridx, int* __restrict__ starts,
    int n_samples, int n_rays)
{
    const int t = blockIdx.x * blockDim.x + threadIdx.x;
    const int i0 = t * 4;
    if (i0 >= n_samples) return;

    int prev = (i0 == 0) ? -1 : ridx[i0 - 1];
    const int nj = min(4, n_samples - i0);
    if (nj == 4) {
        const int4 v = *reinterpret_cast<const int4*>(ridx + i0);
        const int cur[4] = {v.x, v.y, v.z, v.w};
        #pragma unroll
        for (int j = 0; j < 4; ++j) {
            const int c = cur[j];
            for (int r = prev + 1; r <= c; ++r) starts[r] = i0 + j;
            prev = c;
        }
    } else {
        for (int j = 0; j < nj; ++j) {
            const int c = ridx[i0 + j];
            for (int r = prev + 1; r <= c; ++r) starts[r] = i0 + j;
            prev = c;
        }
    }
    if (i0 + 4 >= n_samples) {       // last thread closes the table
        for (int r = prev + 1; r <= n_rays; ++r) starts[r] = n_samples;
    }
}

__global__ __launch_bounds__(256) void render_kernel(
    const float* __restrict__ color,    // [N,3]
    const float* __restrict__ density,  // [N,1]
    const float* __restrict__ deltas,   // [N,1]
    const float* __restrict__ depths,   // [N,1]
    const int*   __restrict__ starts,   // [R+1]
    float*       __restrict__ out,      // rgb[3R] | depth[R] | alpha[R] | hit[R]
    int n_rays)
{
    const int tid = blockIdx.x * blockDim.x + threadIdx.x;
    const int r   = tid >> 4;           // ray id (16 lanes per ray)
    const int sub = tid & 15;           // lane within group (== lane within DPP row)
    if (r >= n_rays) return;

    const int start = starts[r];
    const int end   = starts[r + 1];

    float carry = 0.0f;                 // cumulative tau from previous chunks
    float aw = 0.0f, ar = 0.0f, ag = 0.0f, ab = 0.0f, ad = 0.0f;

    for (int base = start; base < end; base += 16) {
        const int i = base + sub;
        const bool valid = (i < end);
        float tau = 0.0f, c0 = 0.0f, c1 = 0.0f, c2 = 0.0f, dp = 0.0f;
        if (valid) {
            tau = density[i] * deltas[i];
            c0  = color[3 * i + 0];
            c1  = color[3 * i + 1];
            c2  = color[3 * i + 2];
            dp  = depths[i];
        }
        // inclusive scan of tau within the 16-lane group (DPP, VALU-only)
        const float x = row16_inclusive_scan(tau);
        const float excl = carry + (x - tau);       // exclusive segmented cumsum
        const float w = __expf(-excl) * (1.0f - __expf(-tau));
        aw += w;
        ar += w * c0;
        ag += w * c1;
        ab += w * c2;
        ad += w * dp;
        carry += __shfl(x, 15, 16);                 // chunk total broadcast
        if (carry >= THR_TAU) break;                // extinction: rest <= e^-7
    }

    // group reduction via Hillis-Steele: lane 15 ends with the group totals
    aw = row16_inclusive_scan(aw);
    ar = row16_inclusive_scan(ar);
    ag = row16_inclusive_scan(ag);
    ab = row16_inclusive_scan(ab);
    ad = row16_inclusive_scan(ad);

    if (sub == 15) {
        const float alpha = aw;
        out[3 * r + 0] = (1.0f - alpha) + alpha * ar;   // white background composite
        out[3 * r + 1] = (1.0f - alpha) + alpha * ag;
        out[3 * r + 2] = (1.0f - alpha) + alpha * ab;
        out[3 * n_rays + r] = ad;                       // depth
        out[4 * n_rays + r] = alpha;                    // alpha
        out[5 * n_rays + r] = (alpha > 0.0f) ? 1.0f : 0.0f;  // hit
    }
}

// ---------------- fallback (ws too small): thread-per-ray, binary search ----
__global__ __launch_bounds__(256) void render_fallback(
    const float* __restrict__ color, const float* __restrict__ density,
    const float* __restrict__ deltas, const float* __restrict__ depths,
    const int* __restrict__ ridx, float* __restrict__ out,
    int n_samples, int n_rays)
{
    const int r = blockIdx.x * blockDim.x + threadIdx.x;
    if (r >= n_rays) return;
    int lo = 0, hi = n_samples;
    while (lo < hi) { int m = (lo + hi) >> 1; if (ridx[m] < r) lo = m + 1; else hi = m; }
    int i = lo; int lo2 = lo; hi = n_samples;
    while (lo2 < hi) { int m = (lo2 + hi) >> 1; if (ridx[m] < r + 1) lo2 = m + 1; else hi = m; }
    const int e = lo2;
    float T = 1.f, aw = 0.f, ar = 0.f, ag = 0.f, ab = 0.f, ad = 0.f;
    for (; i < e && T > 1e-5f; ++i) {
        const float t = density[i] * deltas[i];
        const float ee = __expf(-t);
        const float w = T * (1.f - ee);
        aw += w; ar += w * color[3*i]; ag += w * color[3*i+1];
        ab += w * color[3*i+2]; ad += w * depths[i];
        T *= ee;
    }
    const float alpha = aw;
    out[3 * r + 0] = (1.0f - alpha) + alpha * ar;
    out[3 * r + 1] = (1.0f - alpha) + alpha * ag;
    out[3 * r + 2] = (1.0f - alpha) + alpha * ab;
    out[3 * n_rays + r] = ad;
    out[4 * n_rays + r] = alpha;
    out[5 * n_rays + r] = (alpha > 0.0f) ? 1.0f : 0.0f;
}

extern "C" void kernel_launch(void* const* d_in, const int* in_sizes, int n_in,
                              void* d_out, int out_size, void* d_ws, size_t ws_size,
                              hipStream_t stream) {
    const float* color   = (const float*)d_in[0];
    const float* density = (const float*)d_in[1];
    const float* deltas  = (const float*)d_in[2];
    const float* depths  = (const float*)d_in[3];
    const int*   ridx    = (const int*)d_in[4];
    float* out = (float*)d_out;

    const int n_samples = in_sizes[1];      // density element count == N
    const int n_rays    = out_size / 6;     // rgb(3R) + depth(R) + alpha(R) + hit(R)

    const size_t starts_bytes = (size_t)(n_rays + 1) * sizeof(int);

    if (ws_size >= starts_bytes) {
        int* starts = (int*)d_ws;
        const int snthreads = (n_samples + 3) / 4;
        const int sblocks = (snthreads + 255) / 256;
        starts_kernel<<<sblocks, 256, 0, stream>>>(ridx, starts, n_samples, n_rays);

        const long long nthr = (long long)n_rays * 16;
        const int rblocks = (int)((nthr + 255) / 256);
        render_kernel<<<rblocks, 256, 0, stream>>>(
            color, density, deltas, depths, starts, out, n_rays);
    } else {
        const int rblocks = (n_rays + 255) / 256;
        render_fallback<<<rblocks, 256, 0, stream>>>(
            color, density, deltas, depths, ridx, out, n_samples, n_rays);
    }
}